// Round 2
// baseline (542.725 us; speedup 1.0000x reference)
//
#include <hip/hip_runtime.h>
#include <stdint.h>

#define N_NODES 20000
#define N_EDGES 100000

typedef __bf16 bf16;
typedef bf16  bf16x8 __attribute__((ext_vector_type(8)));
typedef float f32x4  __attribute__((ext_vector_type(4)));

__device__ __forceinline__ f32x4 mfma16(bf16x8 a, bf16x8 b, f32x4 c) {
  return __builtin_amdgcn_mfma_f32_16x16x32_bf16(a, b, c, 0, 0, 0);
}

__device__ __forceinline__ float silu_(float y) {
  return y / (1.0f + __expf(-y));
}

// ---- workspace layout (bytes) ----
// all weights pre-transposed to [n][k] (K contiguous) and pre-scaled, bf16
#define OFF_W0T   0u          // [64][32]   mlp_w0/sqrt(8), K zero-padded 8->32
#define OFF_W1T   4096u       // [64][64]   mlp_w1 * SILU_NORM/8
#define OFF_W2T   12288u      // [64][64]   mlp_w2 * SILU_NORM/8
#define OFF_W3T   20480u      // [512][64]  mlp_w3 * SILU_NORM/8
#define OFF_WOS   86016u      // [128][256] W_out_s/16 * (u<128 ? PW_0E : PW_0E*INV_SQRT3)
#define OFF_WOV   151552u     // [128][256] W_out_v/16 * PW_0E   (PW_1O*INV_SQRT3 == PW_0E)
#define OFF_WST   217088u     // [128][128] W_up_s/sqrt(128)
#define OFF_WVT   249856u     // [128][128] W_up_v/sqrt(128)
#define OFF_SUP   282624u     // [20000][128] bf16 s_up
#define OFF_VUP   5402624u    // [20000][384] bf16 v_up, layout [n][i][u]

// ---------------- K0: weight prep (transpose + scale + bf16) ----------------
__global__ __launch_bounds__(256) void k0_prep(
    const float* __restrict__ wus, const float* __restrict__ wuv,
    const float* __restrict__ w0,  const float* __restrict__ w1,
    const float* __restrict__ w2,  const float* __restrict__ w3,
    const float* __restrict__ wos_g, const float* __restrict__ wov_g,
    char* __restrict__ ws) {
  const int idx = blockIdx.x * 256 + threadIdx.x;  // 0..32767
  bf16* W0T = (bf16*)(ws + OFF_W0T);
  bf16* W1T = (bf16*)(ws + OFF_W1T);
  bf16* W2T = (bf16*)(ws + OFF_W2T);
  bf16* W3T = (bf16*)(ws + OFF_W3T);
  bf16* WOS = (bf16*)(ws + OFF_WOS);
  bf16* WOV = (bf16*)(ws + OFF_WOV);
  bf16* WST = (bf16*)(ws + OFF_WST);
  bf16* WVT = (bf16*)(ws + OFF_WVT);

  const float cS   = 0.08838834764831845f;   // 1/sqrt(128)
  const float c0   = 0.35355339059327373f;   // 1/sqrt(8)
  const float c12  = 1.6790390826f / 8.0f;   // SILU_NORM/sqrt(64)
  const float cosA = 0.04419417382415922f;   // PW_0E/16
  const float cosB = 0.025515518153991442f;  // PW_0E*INV_SQRT3/16
  const float cov  = 0.04419417382415922f;   // PW_1O*INV_SQRT3/16 == PW_0E/16

  if (idx < 16384) {
    int w = idx >> 7, u = idx & 127;
    WST[idx] = (bf16)(wus[u * 128 + w] * cS);
    WVT[idx] = (bf16)(wuv[u * 128 + w] * cS);
  }
  if (idx < 2048) {
    int h = idx >> 5, r = idx & 31;
    W0T[idx] = (bf16)((r < 8) ? w0[r * 64 + h] * c0 : 0.0f);
  }
  if (idx < 4096) {
    int h = idx >> 6, k = idx & 63;
    W1T[idx] = (bf16)(w1[k * 64 + h] * c12);
    W2T[idx] = (bf16)(w2[k * 64 + h] * c12);
  }
  {
    int j = idx >> 6, k = idx & 63;
    W3T[idx] = (bf16)(w3[k * 512 + j] * c12);
    int w = idx >> 8, u = idx & 255;
    WOS[idx] = (bf16)(wos_g[u * 128 + w] * ((u < 128) ? cosA : cosB));
    WOV[idx] = (bf16)(wov_g[u * 128 + w] * cov);
  }
}

// ---------------- K1: node up-projection ----------------
// grid (313, 4): blockIdx.y = stream (0: s, 1..3: v component i)
__global__ __launch_bounds__(256) void k1_nodeup(const float* __restrict__ nf,
                                                 char* __restrict__ ws) {
  __shared__ bf16 At[64 * 136];  // 64 rows x 128 K, padded +8
  const int n0 = blockIdx.x * 64;
  const int sid = blockIdx.y;
  const int t = threadIdx.x;

  #pragma unroll
  for (int p = 0; p < 32; p++) {
    int idx = t + p * 256;       // 0..8191
    int r = idx >> 7, k = idx & 127;
    int node = n0 + r;
    float v = 0.0f;
    if (node < N_NODES)
      v = (sid == 0) ? nf[node * 512 + k]
                     : nf[node * 512 + 128 + 3 * k + (sid - 1)];
    At[r * 136 + k] = (bf16)v;
  }
  __syncthreads();

  const bf16* BT = (const bf16*)(ws + ((sid == 0) ? OFF_WST : OFF_WVT));
  const int lane = t & 63, wv = t >> 6;
  const int m = lane & 15, q = lane >> 4;
  const int m0 = wv * 16;

  const f32x4 z = {0.f, 0.f, 0.f, 0.f};
  f32x4 acc[8] = {z, z, z, z, z, z, z, z};
  #pragma unroll
  for (int kk = 0; kk < 128; kk += 32) {
    bf16x8 af = *(const bf16x8*)&At[(m0 + m) * 136 + kk + q * 8];
    #pragma unroll
    for (int nt = 0; nt < 8; nt++) {
      bf16x8 bfr = *(const bf16x8*)&BT[(nt * 16 + m) * 128 + kk + q * 8];
      acc[nt] = mfma16(af, bfr, acc[nt]);
    }
  }

  bf16* sup = (bf16*)(ws + OFF_SUP);
  bf16* vup = (bf16*)(ws + OFF_VUP);
  #pragma unroll
  for (int nt = 0; nt < 8; nt++) {
    int col = nt * 16 + m;
    #pragma unroll
    for (int r = 0; r < 4; r++) {
      int row = m0 + q * 4 + r;
      int node = n0 + row;
      if (node < N_NODES) {
        if (sid == 0) sup[node * 128 + col] = (bf16)acc[nt][r];
        else          vup[node * 384 + (sid - 1) * 128 + col] = (bf16)acc[nt][r];
      }
    }
  }
}

// ---------------- K2: edge MLP -> tpw (written into d_out) ----------------
__global__ __launch_bounds__(256) void k2_mlp(const float* __restrict__ efeat,
                                              const char* __restrict__ ws,
                                              float* __restrict__ tpw) {
  __shared__ bf16 A0[64 * 40];
  __shared__ bf16 hA[64 * 72];
  __shared__ bf16 hB[64 * 72];
  const int e0 = blockIdx.x * 64;
  const int t = threadIdx.x;
  const int lane = t & 63, wv = t >> 6;
  const int m = lane & 15, q = lane >> 4;
  const int m0 = wv * 16;
  const f32x4 z = {0.f, 0.f, 0.f, 0.f};

  #pragma unroll
  for (int p = 0; p < 8; p++) {
    int idx = t + p * 256;       // 0..2047
    int r = idx >> 5, k = idx & 31;
    int e = e0 + r;
    float v = (k < 8 && e < N_EDGES) ? efeat[e * 8 + k] : 0.0f;
    A0[r * 40 + k] = (bf16)v;
  }
  __syncthreads();

  const bf16* W0T = (const bf16*)(ws + OFF_W0T);
  const bf16* W1T = (const bf16*)(ws + OFF_W1T);
  const bf16* W2T = (const bf16*)(ws + OFF_W2T);
  const bf16* W3T = (const bf16*)(ws + OFF_W3T);

  { // layer 0: (64x32pad) @ (32x64)
    f32x4 acc[4] = {z, z, z, z};
    bf16x8 af = *(const bf16x8*)&A0[(m0 + m) * 40 + q * 8];
    #pragma unroll
    for (int nt = 0; nt < 4; nt++) {
      bf16x8 bfr = *(const bf16x8*)&W0T[(nt * 16 + m) * 32 + q * 8];
      acc[nt] = mfma16(af, bfr, acc[nt]);
    }
    #pragma unroll
    for (int nt = 0; nt < 4; nt++)
      #pragma unroll
      for (int r = 0; r < 4; r++)
        hA[(m0 + q * 4 + r) * 72 + nt * 16 + m] = (bf16)silu_(acc[nt][r]);
  }
  __syncthreads();

  { // layer 1: hA @ W1T -> hB
    f32x4 acc[4] = {z, z, z, z};
    #pragma unroll
    for (int kk = 0; kk < 64; kk += 32) {
      bf16x8 af = *(const bf16x8*)&hA[(m0 + m) * 72 + kk + q * 8];
      #pragma unroll
      for (int nt = 0; nt < 4; nt++) {
        bf16x8 bfr = *(const bf16x8*)&W1T[(nt * 16 + m) * 64 + kk + q * 8];
        acc[nt] = mfma16(af, bfr, acc[nt]);
      }
    }
    #pragma unroll
    for (int nt = 0; nt < 4; nt++)
      #pragma unroll
      for (int r = 0; r < 4; r++)
        hB[(m0 + q * 4 + r) * 72 + nt * 16 + m] = (bf16)silu_(acc[nt][r]);
  }
  __syncthreads();

  { // layer 2: hB @ W2T -> hA
    f32x4 acc[4] = {z, z, z, z};
    #pragma unroll
    for (int kk = 0; kk < 64; kk += 32) {
      bf16x8 af = *(const bf16x8*)&hB[(m0 + m) * 72 + kk + q * 8];
      #pragma unroll
      for (int nt = 0; nt < 4; nt++) {
        bf16x8 bfr = *(const bf16x8*)&W2T[(nt * 16 + m) * 64 + kk + q * 8];
        acc[nt] = mfma16(af, bfr, acc[nt]);
      }
    }
    __syncthreads();  // all layer-2 reads of hB complete before hA is rewritten
    #pragma unroll
    for (int nt = 0; nt < 4; nt++)
      #pragma unroll
      for (int r = 0; r < 4; r++)
        hA[(m0 + q * 4 + r) * 72 + nt * 16 + m] = (bf16)silu_(acc[nt][r]);
  }
  __syncthreads();

  { // layer 3: hA(64x64) @ W3T(512x64) -> tpw rows e0..e0+63
    bf16x8 af0 = *(const bf16x8*)&hA[(m0 + m) * 72 + 0  + q * 8];
    bf16x8 af1 = *(const bf16x8*)&hA[(m0 + m) * 72 + 32 + q * 8];
    const int row0 = m0 + q * 4;
    #pragma unroll 4
    for (int nt = 0; nt < 32; nt++) {
      f32x4 acc = z;
      bf16x8 b0 = *(const bf16x8*)&W3T[(nt * 16 + m) * 64 + q * 8];
      bf16x8 b1 = *(const bf16x8*)&W3T[(nt * 16 + m) * 64 + 32 + q * 8];
      acc = mfma16(af0, b0, acc);
      acc = mfma16(af1, b1, acc);
      int col = nt * 16 + m;
      #pragma unroll
      for (int r = 0; r < 4; r++) {
        int e = e0 + row0 + r;
        if (e < N_EDGES) tpw[e * 512 + col] = acc[r];
      }
    }
  }
}

// ---------------- K3: tensor product + output projection ----------------
// block: 32 edges -> 128 MFMA rows: rows 0..31 = s-rows (B=W_out_s),
// rows 32+i*32+eL = v-rows for component i (B=W_out_v). K=256 in 4 chunks.
__global__ __launch_bounds__(256) void k3_tp_out(const float* __restrict__ attrs,
                                                 const int* __restrict__ sender,
                                                 const char* __restrict__ ws,
                                                 float* out) {
  __shared__ bf16 A[128 * 72];
  __shared__ int   sLDS[32];
  __shared__ float aLDS[128];
  const int e0 = blockIdx.x * 32;
  const int t = threadIdx.x;
  if (t < 32) sLDS[t] = sender[e0 + t];
  if (t < 128) aLDS[t] = attrs[e0 * 4 + t];
  __syncthreads();

  const bf16* sup = (const bf16*)(ws + OFF_SUP);
  const bf16* vup = (const bf16*)(ws + OFF_VUP);
  const int lane = t & 63, wv = t >> 6;
  const int m = lane & 15, q = lane >> 4;
  const bf16* WB = (const bf16*)(ws + ((wv == 0) ? OFF_WOS : OFF_WOV));

  // staging role: 2 threads per A-row, 32 K each
  const int srow = t >> 1;
  const int kh = (t & 1) * 32;
  const bool isS = (srow < 32);
  const int ii = isS ? 0 : ((srow - 32) >> 5);
  const int eL = isS ? srow : ((srow - 32) & 31);
  const int eG = e0 + eL;
  const int se = sLDS[eL];
  const float s0  = aLDS[eL * 4 + 0];
  const float s1x = aLDS[eL * 4 + 1];
  const float s1y = aLDS[eL * 4 + 2];
  const float s1z = aLDS[eL * 4 + 3];
  const float s1i = (ii == 0) ? s1x : ((ii == 1) ? s1y : s1z);
  const float* tpr = out + (size_t)eG * 512;  // tpw row (written by K2)
  const bf16* supR = sup + se * 128;
  const bf16* vupR = vup + se * 384;

  const f32x4 z = {0.f, 0.f, 0.f, 0.f};
  f32x4 acc0[8] = {z, z, z, z, z, z, z, z};
  f32x4 acc1[8] = {z, z, z, z, z, z, z, z};

  for (int kc = 0; kc < 4; kc++) {
    if (kc) __syncthreads();
    if (kc < 2) {
      const int ub = kc * 64 + kh;          // u = ub + j, u < 128
      if (isS) {
        #pragma unroll 8
        for (int j = 0; j < 32; j++) {
          int u = ub + j;
          A[srow * 72 + kh + j] = (bf16)(tpr[u] * (float)supR[u] * s0);     // w00*ss*sh0
        }
      } else {
        #pragma unroll 8
        for (int j = 0; j < 32; j++) {
          int u = ub + j;
          A[srow * 72 + kh + j] = (bf16)(tpr[128 + u] * (float)supR[u] * s1i); // w01*ss*sh1_i
        }
      }
    } else {
      const int ub = (kc - 2) * 64 + kh;    // u' = ub + j
      if (isS) {
        #pragma unroll 8
        for (int j = 0; j < 32; j++) {
          int up = ub + j;
          float dv = (float)vupR[up] * s1x + (float)vupR[128 + up] * s1y +
                     (float)vupR[256 + up] * s1z;
          A[srow * 72 + kh + j] = (bf16)(tpr[384 + up] * dv);               // w11*(vs.sh1)
        }
      } else {
        #pragma unroll 8
        for (int j = 0; j < 32; j++) {
          int up = ub + j;
          A[srow * 72 + kh + j] =
              (bf16)(tpr[256 + up] * s0 * (float)vupR[ii * 128 + up]);      // w10*sh0*vs_i
        }
      }
    }
    __syncthreads();

    const int kb = kc * 64;
    #pragma unroll
    for (int kk = 0; kk < 64; kk += 32) {
      bf16x8 af0 = *(const bf16x8*)&A[(wv * 32 + m) * 72 + kk + q * 8];
      bf16x8 af1 = *(const bf16x8*)&A[(wv * 32 + 16 + m) * 72 + kk + q * 8];
      #pragma unroll
      for (int nt = 0; nt < 8; nt++) {
        bf16x8 bfr = *(const bf16x8*)&WB[(nt * 16 + m) * 256 + kb + kk + q * 8];
        acc0[nt] = mfma16(af0, bfr, acc0[nt]);
        acc1[nt] = mfma16(af1, bfr, acc1[nt]);
      }
    }
  }

  // epilogue (all tpw reads for this block completed before the last barrier)
  #pragma unroll
  for (int b = 0; b < 2; b++) {
    const f32x4* accp = b ? acc1 : acc0;
    int rb = wv * 32 + b * 16 + q * 4;
    #pragma unroll
    for (int nt = 0; nt < 8; nt++) {
      int col = nt * 16 + m;
      #pragma unroll
      for (int r = 0; r < 4; r++) {
        int row = rb + r;
        float v = accp[nt][r];
        if (wv == 0) {
          out[(size_t)(e0 + row) * 512 + col] = v;                    // out_s
        } else {
          int i2 = (row - 32) >> 5, eL2 = (row - 32) & 31;
          out[(size_t)(e0 + eL2) * 512 + 128 + 3 * col + i2] = v;     // out_v[w][i]
        }
      }
    }
  }
}

extern "C" void kernel_launch(void* const* d_in, const int* in_sizes, int n_in,
                              void* d_out, int out_size, void* d_ws, size_t ws_size,
                              hipStream_t stream) {
  const float* node_feats = (const float*)d_in[0];
  const float* edge_attrs = (const float*)d_in[1];
  const float* edge_feats = (const float*)d_in[2];
  const int*   edge_index = (const int*)d_in[3];   // [2][N_EDGES], row 0 = sender
  const float* W_up_s = (const float*)d_in[4];
  const float* W_up_v = (const float*)d_in[5];
  const float* w0 = (const float*)d_in[6];
  const float* w1 = (const float*)d_in[7];
  const float* w2 = (const float*)d_in[8];
  const float* w3 = (const float*)d_in[9];
  const float* Wos = (const float*)d_in[10];
  const float* Wov = (const float*)d_in[11];
  float* out = (float*)d_out;
  char* ws = (char*)d_ws;

  k0_prep<<<dim3(128), dim3(256), 0, stream>>>(W_up_s, W_up_v, w0, w1, w2, w3,
                                               Wos, Wov, ws);
  k1_nodeup<<<dim3(313, 4), dim3(256), 0, stream>>>(node_feats, ws);
  k2_mlp<<<dim3(1563), dim3(256), 0, stream>>>(edge_feats, ws, out);   // tpw -> d_out
  k3_tp_out<<<dim3(3125), dim3(256), 0, stream>>>(edge_attrs, edge_index, ws, out);
}

// Round 3
// 460.551 us; speedup vs baseline: 1.1784x; 1.1784x over previous
//
#include <hip/hip_runtime.h>
#include <stdint.h>

#define N_NODES 20000
#define N_EDGES 100000

typedef __bf16 bf16;
typedef bf16  bf16x8 __attribute__((ext_vector_type(8)));
typedef float f32x4  __attribute__((ext_vector_type(4)));

__device__ __forceinline__ f32x4 mfma16(bf16x8 a, bf16x8 b, f32x4 c) {
  return __builtin_amdgcn_mfma_f32_16x16x32_bf16(a, b, c, 0, 0, 0);
}

__device__ __forceinline__ float silu_(float y) {
  return y / (1.0f + __expf(-y));
}

// ---- workspace layout (bytes) ----
#define OFF_W0T   0u          // [64][32]   mlp_w0/sqrt(8), K zero-padded 8->32
#define OFF_W1T   4096u       // [64][64]   mlp_w1 * SILU_NORM/8
#define OFF_W2T   12288u      // [64][64]   mlp_w2 * SILU_NORM/8
#define OFF_W3T   20480u      // [512][64]  mlp_w3 * SILU_NORM/8
#define OFF_WOS   86016u      // [128][256] W_out_s/16 * (u<128 ? PW_0E : PW_0E*INV_SQRT3)
#define OFF_WOV   151552u     // [128][256] W_out_v/16 * PW_0E   (PW_1O*INV_SQRT3 == PW_0E)
#define OFF_WST   217088u     // [128][128] W_up_s/sqrt(128)
#define OFF_WVT   249856u     // [128][128] W_up_v/sqrt(128)
#define OFF_SUP   282624u     // [20000][128] bf16 s_up
#define OFF_VUP   5402624u    // [20000][384] bf16 v_up, layout [n][i][u]

// ---------------- K0: weight prep (transpose + scale + bf16) ----------------
__global__ __launch_bounds__(256) void k0_prep(
    const float* __restrict__ wus, const float* __restrict__ wuv,
    const float* __restrict__ w0,  const float* __restrict__ w1,
    const float* __restrict__ w2,  const float* __restrict__ w3,
    const float* __restrict__ wos_g, const float* __restrict__ wov_g,
    char* __restrict__ ws) {
  const int idx = blockIdx.x * 256 + threadIdx.x;  // 0..32767
  bf16* W0T = (bf16*)(ws + OFF_W0T);
  bf16* W1T = (bf16*)(ws + OFF_W1T);
  bf16* W2T = (bf16*)(ws + OFF_W2T);
  bf16* W3T = (bf16*)(ws + OFF_W3T);
  bf16* WOS = (bf16*)(ws + OFF_WOS);
  bf16* WOV = (bf16*)(ws + OFF_WOV);
  bf16* WST = (bf16*)(ws + OFF_WST);
  bf16* WVT = (bf16*)(ws + OFF_WVT);

  const float cS   = 0.08838834764831845f;   // 1/sqrt(128)
  const float c0   = 0.35355339059327373f;   // 1/sqrt(8)
  const float c12  = 1.6790390826f / 8.0f;   // SILU_NORM/sqrt(64)
  const float cosA = 0.04419417382415922f;   // PW_0E/16
  const float cosB = 0.025515518153991442f;  // PW_0E*INV_SQRT3/16
  const float cov  = 0.04419417382415922f;   // PW_1O*INV_SQRT3/16 == PW_0E/16

  if (idx < 16384) {
    int w = idx >> 7, u = idx & 127;
    WST[idx] = (bf16)(wus[u * 128 + w] * cS);
    WVT[idx] = (bf16)(wuv[u * 128 + w] * cS);
  }
  if (idx < 2048) {
    int h = idx >> 5, r = idx & 31;
    W0T[idx] = (bf16)((r < 8) ? w0[r * 64 + h] * c0 : 0.0f);
  }
  if (idx < 4096) {
    int h = idx >> 6, k = idx & 63;
    W1T[idx] = (bf16)(w1[k * 64 + h] * c12);
    W2T[idx] = (bf16)(w2[k * 64 + h] * c12);
  }
  {
    int j = idx >> 6, k = idx & 63;
    W3T[idx] = (bf16)(w3[k * 512 + j] * c12);
    int w = idx >> 8, u = idx & 255;
    WOS[idx] = (bf16)(wos_g[u * 128 + w] * ((u < 128) ? cosA : cosB));
    WOV[idx] = (bf16)(wov_g[u * 128 + w] * cov);
  }
}

// ---------------- K1: node up-projection ----------------
// one block = 32 nodes, all 4 streams; wave w computes stream w.
// 20000 = 625 * 32 exactly -> no bounds checks.
__global__ __launch_bounds__(256, 4) void k1_nodeup(const float* __restrict__ nf,
                                                    char* __restrict__ ws) {
  __shared__ __align__(16) bf16 tiles[4][32 * 136];  // [stream][row][K pad 136]
  const int n0 = blockIdx.x * 32;
  const int t = threadIdx.x;

  // coalesced float4 load of 32x512 f32, scatter to component tiles
  #pragma unroll
  for (int p = 0; p < 16; p++) {
    int idx = p * 256 + t;           // 0..4095
    int r = idx >> 7, c4 = idx & 127;
    const float4 f = *(const float4*)&nf[(size_t)(n0 + r) * 512 + c4 * 4];
    float vals[4] = {f.x, f.y, f.z, f.w};
    #pragma unroll
    for (int e2 = 0; e2 < 4; e2++) {
      int g = c4 * 4 + e2;
      if (g < 128) {
        tiles[0][r * 136 + g] = (bf16)vals[e2];
      } else {
        int gg = g - 128;
        int u = gg / 3, i = gg - 3 * u;
        tiles[1 + i][r * 136 + u] = (bf16)vals[e2];
      }
    }
  }
  __syncthreads();

  const int wv = t >> 6, lane = t & 63;
  const int m = lane & 15, q = lane >> 4;
  const bf16* BT = (const bf16*)(ws + ((wv == 0) ? OFF_WST : OFF_WVT));
  const bf16* At = tiles[wv];

  const f32x4 z = {0.f, 0.f, 0.f, 0.f};
  f32x4 acc[2][8] = {{z, z, z, z, z, z, z, z}, {z, z, z, z, z, z, z, z}};
  #pragma unroll
  for (int kk = 0; kk < 128; kk += 32) {
    bf16x8 af0 = *(const bf16x8*)&At[m * 136 + kk + q * 8];
    bf16x8 af1 = *(const bf16x8*)&At[(16 + m) * 136 + kk + q * 8];
    #pragma unroll
    for (int nt = 0; nt < 8; nt++) {
      bf16x8 bfr = *(const bf16x8*)&BT[(nt * 16 + m) * 128 + kk + q * 8];
      acc[0][nt] = mfma16(af0, bfr, acc[0][nt]);
      acc[1][nt] = mfma16(af1, bfr, acc[1][nt]);
    }
  }

  bf16* sup = (bf16*)(ws + OFF_SUP);
  bf16* vup = (bf16*)(ws + OFF_VUP);
  #pragma unroll
  for (int rt = 0; rt < 2; rt++) {
    #pragma unroll
    for (int nt = 0; nt < 8; nt++) {
      int col = nt * 16 + m;
      #pragma unroll
      for (int r = 0; r < 4; r++) {
        int node = n0 + rt * 16 + q * 4 + r;
        if (wv == 0) sup[node * 128 + col] = (bf16)acc[rt][nt][r];
        else         vup[node * 384 + (wv - 1) * 128 + col] = (bf16)acc[rt][nt][r];
      }
    }
  }
}

// ---------------- K23: fused edge MLP + tensor product + out-projection ----
// block = 32 edges (100000 = 3125*32 exactly), 256 threads.
// LDS: tpw 32x520 bf16 (33280 B) | A 128x72 bf16 (18432 B, aliases MLP scratch)
//      | sLDS 128 B | aLDS 512 B  => 52352 B -> 3 blocks/CU.
#define SM_TPW 0
#define SM_A   33280
#define SM_A0  33280              /* 32x40 bf16 = 2560 (alias of A) */
#define SM_H0  (33280 + 2560)     /* 32x72 bf16 = 4608 */
#define SM_H1  (33280 + 7168)     /* 32x72 bf16 = 4608 */
#define SM_SND 51712
#define SM_ATT 51840
#define TPW_LD 520

__global__ __launch_bounds__(256, 3) void k23_fused(
    const float* __restrict__ efeat, const float* __restrict__ attrs,
    const int* __restrict__ sender, const char* __restrict__ ws,
    float* __restrict__ out) {
  __shared__ __align__(16) char smem[52352];
  bf16* tpwL = (bf16*)(smem + SM_TPW);
  bf16* A    = (bf16*)(smem + SM_A);
  bf16* A0e  = (bf16*)(smem + SM_A0);
  bf16* h0   = (bf16*)(smem + SM_H0);
  bf16* h1   = (bf16*)(smem + SM_H1);
  int*  sLDS = (int*)(smem + SM_SND);
  float* aLDS = (float*)(smem + SM_ATT);

  const int e0 = blockIdx.x * 32;
  const int t = threadIdx.x;
  const int wv = t >> 6, lane = t & 63;
  const int m = lane & 15, q = lane >> 4;
  const f32x4 z = {0.f, 0.f, 0.f, 0.f};

  // ---- load edge inputs ----
  {
    int r = t >> 3, k = t & 7;                       // 32x8 floats exactly
    A0e[r * 40 + k] = (bf16)efeat[(e0 + r) * 8 + k];
    #pragma unroll
    for (int pp = 0; pp < 3; pp++) {                 // zero-pad cols 8..31
      int pidx = t * 3 + pp;
      int r2 = pidx / 24, k2 = 8 + pidx % 24;
      A0e[r2 * 40 + k2] = (bf16)0.0f;
    }
    if (t < 32) sLDS[t] = sender[e0 + t];
    if (t < 128) aLDS[t] = attrs[e0 * 4 + t];
  }
  __syncthreads();

  const bf16* W0T = (const bf16*)(ws + OFF_W0T);
  const bf16* W1T = (const bf16*)(ws + OFF_W1T);
  const bf16* W2T = (const bf16*)(ws + OFF_W2T);
  const bf16* W3T = (const bf16*)(ws + OFF_W3T);

  // MLP tiling: rt = wv&1 (row-tile of 16), nh = wv>>1 (N-half)
  const int rt = wv & 1, nh = wv >> 1;

  { // layer 0: (32x32pad) @ (32x64) -> h0
    f32x4 acc[2] = {z, z};
    bf16x8 af = *(const bf16x8*)&A0e[(rt * 16 + m) * 40 + q * 8];
    #pragma unroll
    for (int ntl = 0; ntl < 2; ntl++) {
      int ntg = nh * 2 + ntl;
      bf16x8 bfr = *(const bf16x8*)&W0T[(ntg * 16 + m) * 32 + q * 8];
      acc[ntl] = mfma16(af, bfr, acc[ntl]);
    }
    __syncthreads();   // A0e reads done before h0 writes (h0 doesn't alias A0e, but keep MLP strict)
    #pragma unroll
    for (int ntl = 0; ntl < 2; ntl++)
      #pragma unroll
      for (int r = 0; r < 4; r++)
        h0[(rt * 16 + q * 4 + r) * 72 + (nh * 2 + ntl) * 16 + m] = (bf16)silu_(acc[ntl][r]);
  }
  __syncthreads();

  { // layer 1: h0 @ W1T -> h1
    f32x4 acc[2] = {z, z};
    #pragma unroll
    for (int kk = 0; kk < 64; kk += 32) {
      bf16x8 af = *(const bf16x8*)&h0[(rt * 16 + m) * 72 + kk + q * 8];
      #pragma unroll
      for (int ntl = 0; ntl < 2; ntl++) {
        int ntg = nh * 2 + ntl;
        bf16x8 bfr = *(const bf16x8*)&W1T[(ntg * 16 + m) * 64 + kk + q * 8];
        acc[ntl] = mfma16(af, bfr, acc[ntl]);
      }
    }
    __syncthreads();
    #pragma unroll
    for (int ntl = 0; ntl < 2; ntl++)
      #pragma unroll
      for (int r = 0; r < 4; r++)
        h1[(rt * 16 + q * 4 + r) * 72 + (nh * 2 + ntl) * 16 + m] = (bf16)silu_(acc[ntl][r]);
  }
  __syncthreads();

  { // layer 2: h1 @ W2T -> h0 (reused)
    f32x4 acc[2] = {z, z};
    #pragma unroll
    for (int kk = 0; kk < 64; kk += 32) {
      bf16x8 af = *(const bf16x8*)&h1[(rt * 16 + m) * 72 + kk + q * 8];
      #pragma unroll
      for (int ntl = 0; ntl < 2; ntl++) {
        int ntg = nh * 2 + ntl;
        bf16x8 bfr = *(const bf16x8*)&W2T[(ntg * 16 + m) * 64 + kk + q * 8];
        acc[ntl] = mfma16(af, bfr, acc[ntl]);
      }
    }
    __syncthreads();
    #pragma unroll
    for (int ntl = 0; ntl < 2; ntl++)
      #pragma unroll
      for (int r = 0; r < 4; r++)
        h0[(rt * 16 + q * 4 + r) * 72 + (nh * 2 + ntl) * 16 + m] = (bf16)silu_(acc[ntl][r]);
  }
  __syncthreads();

  { // layer 3: h0(32x64) @ W3T(512x64) -> tpwL (bf16, stride 520)
    bf16x8 af0 = *(const bf16x8*)&h0[(rt * 16 + m) * 72 + 0  + q * 8];
    bf16x8 af1 = *(const bf16x8*)&h0[(rt * 16 + m) * 72 + 32 + q * 8];
    #pragma unroll 4
    for (int i = 0; i < 16; i++) {
      int ntg = nh * 16 + i;
      f32x4 acc = z;
      bf16x8 b0 = *(const bf16x8*)&W3T[(ntg * 16 + m) * 64 + q * 8];
      bf16x8 b1 = *(const bf16x8*)&W3T[(ntg * 16 + m) * 64 + 32 + q * 8];
      acc = mfma16(af0, b0, acc);
      acc = mfma16(af1, b1, acc);
      int col = ntg * 16 + m;
      #pragma unroll
      for (int r = 0; r < 4; r++)
        tpwL[(rt * 16 + q * 4 + r) * TPW_LD + col] = (bf16)acc[r];
    }
  }
  __syncthreads();  // tpw ready; MLP scratch reads done -> A region reusable

  // ---- tensor-product staging + out-projection ----
  const bf16* sup = (const bf16*)(ws + OFF_SUP);
  const bf16* vup = (const bf16*)(ws + OFF_VUP);
  const bf16* WB = (const bf16*)(ws + ((wv == 0) ? OFF_WOS : OFF_WOV));

  const int srow = t >> 1;            // A-row this thread stages
  const int kh = (t & 1) * 32;        // K-half
  const bool isS = (srow < 32);
  const int ii = isS ? 0 : ((srow - 32) >> 5);
  const int eL = isS ? srow : ((srow - 32) & 31);
  const int se = sLDS[eL];
  const float s0  = aLDS[eL * 4 + 0];
  const float s1x = aLDS[eL * 4 + 1];
  const float s1y = aLDS[eL * 4 + 2];
  const float s1z = aLDS[eL * 4 + 3];
  const float s1i = (ii == 0) ? s1x : ((ii == 1) ? s1y : s1z);
  const bf16* tpr = tpwL + eL * TPW_LD;
  const bf16* supR = sup + se * 128;
  const bf16* vupR = vup + se * 384;

  f32x4 acc0[8] = {z, z, z, z, z, z, z, z};
  f32x4 acc1[8] = {z, z, z, z, z, z, z, z};

  for (int kc = 0; kc < 4; kc++) {
    if (kc) __syncthreads();
    if (kc < 2) {
      const int ub = kc * 64 + kh;
      if (isS) {
        #pragma unroll
        for (int j0 = 0; j0 < 32; j0 += 8) {
          bf16x8 tv = *(const bf16x8*)&tpr[ub + j0];
          bf16x8 sv = *(const bf16x8*)&supR[ub + j0];
          bf16x8 o;
          #pragma unroll
          for (int e = 0; e < 8; e++)
            o[e] = (bf16)((float)tv[e] * (float)sv[e] * s0);     // w00*ss*sh0
          *(bf16x8*)&A[srow * 72 + kh + j0] = o;
        }
      } else {
        #pragma unroll
        for (int j0 = 0; j0 < 32; j0 += 8) {
          bf16x8 tv = *(const bf16x8*)&tpr[128 + ub + j0];
          bf16x8 sv = *(const bf16x8*)&supR[ub + j0];
          bf16x8 o;
          #pragma unroll
          for (int e = 0; e < 8; e++)
            o[e] = (bf16)((float)tv[e] * (float)sv[e] * s1i);    // w01*ss*sh1_i
          *(bf16x8*)&A[srow * 72 + kh + j0] = o;
        }
      }
    } else {
      const int ub = (kc - 2) * 64 + kh;
      if (isS) {
        #pragma unroll
        for (int j0 = 0; j0 < 32; j0 += 8) {
          bf16x8 tv = *(const bf16x8*)&tpr[384 + ub + j0];
          bf16x8 vx = *(const bf16x8*)&vupR[ub + j0];
          bf16x8 vy = *(const bf16x8*)&vupR[128 + ub + j0];
          bf16x8 vz = *(const bf16x8*)&vupR[256 + ub + j0];
          bf16x8 o;
          #pragma unroll
          for (int e = 0; e < 8; e++) {
            float dv = (float)vx[e] * s1x + (float)vy[e] * s1y + (float)vz[e] * s1z;
            o[e] = (bf16)((float)tv[e] * dv);                    // w11*(vs.sh1)
          }
          *(bf16x8*)&A[srow * 72 + kh + j0] = o;
        }
      } else {
        #pragma unroll
        for (int j0 = 0; j0 < 32; j0 += 8) {
          bf16x8 tv = *(const bf16x8*)&tpr[256 + ub + j0];
          bf16x8 vv = *(const bf16x8*)&vupR[ii * 128 + ub + j0];
          bf16x8 o;
          #pragma unroll
          for (int e = 0; e < 8; e++)
            o[e] = (bf16)((float)tv[e] * s0 * (float)vv[e]);     // w10*sh0*vs_i
          *(bf16x8*)&A[srow * 72 + kh + j0] = o;
        }
      }
    }
    __syncthreads();

    const int kb = kc * 64;
    #pragma unroll
    for (int kk = 0; kk < 64; kk += 32) {
      bf16x8 af0 = *(const bf16x8*)&A[(wv * 32 + m) * 72 + kk + q * 8];
      bf16x8 af1 = *(const bf16x8*)&A[(wv * 32 + 16 + m) * 72 + kk + q * 8];
      #pragma unroll
      for (int nt = 0; nt < 8; nt++) {
        bf16x8 bfr = *(const bf16x8*)&WB[(nt * 16 + m) * 256 + kb + kk + q * 8];
        acc0[nt] = mfma16(af0, bfr, acc0[nt]);
        acc1[nt] = mfma16(af1, bfr, acc1[nt]);
      }
    }
  }

  // epilogue
  #pragma unroll
  for (int b = 0; b < 2; b++) {
    const f32x4* accp = b ? acc1 : acc0;
    int rb = wv * 32 + b * 16 + q * 4;
    #pragma unroll
    for (int nt = 0; nt < 8; nt++) {
      int col = nt * 16 + m;
      #pragma unroll
      for (int r = 0; r < 4; r++) {
        int row = rb + r;
        float v = accp[nt][r];
        if (wv == 0) {
          out[(size_t)(e0 + row) * 512 + col] = v;                // out_s
        } else {
          int i2 = (row - 32) >> 5, eL2 = (row - 32) & 31;
          out[(size_t)(e0 + eL2) * 512 + 128 + 3 * col + i2] = v; // out_v[w][i]
        }
      }
    }
  }
}

extern "C" void kernel_launch(void* const* d_in, const int* in_sizes, int n_in,
                              void* d_out, int out_size, void* d_ws, size_t ws_size,
                              hipStream_t stream) {
  const float* node_feats = (const float*)d_in[0];
  const float* edge_attrs = (const float*)d_in[1];
  const float* edge_feats = (const float*)d_in[2];
  const int*   edge_index = (const int*)d_in[3];
  const float* W_up_s = (const float*)d_in[4];
  const float* W_up_v = (const float*)d_in[5];
  const float* w0 = (const float*)d_in[6];
  const float* w1 = (const float*)d_in[7];
  const float* w2 = (const float*)d_in[8];
  const float* w3 = (const float*)d_in[9];
  const float* Wos = (const float*)d_in[10];
  const float* Wov = (const float*)d_in[11];
  float* out = (float*)d_out;
  char* ws = (char*)d_ws;

  k0_prep<<<dim3(128), dim3(256), 0, stream>>>(W_up_s, W_up_v, w0, w1, w2, w3,
                                               Wos, Wov, ws);
  k1_nodeup<<<dim3(625), dim3(256), 0, stream>>>(node_feats, ws);
  k23_fused<<<dim3(3125), dim3(256), 0, stream>>>(edge_feats, edge_attrs,
                                                  edge_index, ws, out);
}